// Round 9
// baseline (77.016 us; speedup 1.0000x reference)
//
#include <hip/hip_runtime.h>
#include <math.h>

#define B_ 4
#define H_ 12
#define N_ 1025
#define D_ 64
#define HID_ 32
#define TBL_ 3969            // (2*32-1)^2
#define NQT 17               // 64-row tiles in both q and k
#define NBLK (B_ * H_ * NQT) // 816, divisible by 8
#define LOG2E 1.44269504f
#define THR_ 12.0f           // defer-max threshold (log2 domain); p <= 2^12 fits f16

typedef _Float16 half8 __attribute__((ext_vector_type(8)));
typedef __fp16 fp16x2 __attribute__((ext_vector_type(2)));
typedef float f32x4 __attribute__((ext_vector_type(4)));
typedef float f32x16 __attribute__((ext_vector_type(16)));

#if defined(__has_builtin)
#if __has_builtin(__builtin_amdgcn_exp2f)
#define EX2 __builtin_amdgcn_exp2f
#else
#define EX2 exp2f
#endif
#else
#define EX2 exp2f
#endif

// ws layout (bytes):
//   btT @ 0        : 12*3969*4 = 190512
//   akT @ 190512   : 48*1088*4 = 208896   (also the finite overrun pad for btT)
//   Kf  @ 399408   : 48*17*4096*2 = 6684672
//   Vf  @ 7084080  : 6684672              (end 13768752)
#define BTT_OFF 0
#define AKT_OFF 190512
#define KF_OFF 399408
#define VF_OFF 7084080

__device__ __forceinline__ void stage16(const _Float16* gsrc, _Float16* ldst) {
    __builtin_amdgcn_global_load_lds(
        (const __attribute__((address_space(1))) void*)gsrc,
        (__attribute__((address_space(3))) void*)ldst, 16, 0, 0);
}

__device__ __forceinline__ uint32_t pk2(float a, float b) {
    fp16x2 t = __builtin_amdgcn_cvt_pkrtz(a, b);
    return __builtin_bit_cast(uint32_t, t);
}

// ---------------- prep: K/V -> f16 fragment-order tiles for 32x32x16 MFMA.
// Kf frag fk = wk*4+dc : Kf[..fk*512 + l*8 + j] = K[k0+wk*32+(l&31)][dc*16+(l>>5)*8+j]
// Vf frag fv = kc*2+dh : Vf[..fv*512 + l*8 + j] = V[k0+kc*16+(l>>5)*8+j][dh*32+(l&31)]
__global__ __launch_bounds__(256) void prep(
    const float* __restrict__ K, const float* __restrict__ V,
    const float* __restrict__ MU, const float* __restrict__ GAMMA,
    const float* __restrict__ rel, const float* __restrict__ w1,
    const float* __restrict__ b1, const float* __restrict__ w2,
    _Float16* __restrict__ Kf, _Float16* __restrict__ Vf,
    float* __restrict__ akT, float* __restrict__ btT) {
    const int bid = blockIdx.x;
    const int tid = threadIdx.x;
    if (bid < NBLK) {
        __shared__ uint32_t VlsU[64 * 36];  // [d][kpair] packed f16 pairs
        const int bh = bid / NQT, kt = bid % NQT;
        const size_t base = (size_t)bh * (N_ * D_);
        const int k0 = kt * 64;
        const int lane = tid & 63, q5 = lane & 31, hi = lane >> 5;
        const int fbh = tid >> 6;
        const size_t tb = (size_t)(bh * NQT + kt) * 4096;
        // ---- K fragment loads issued first (consumed after the barrier)
        float4 kld[2][2];
#pragma unroll
        for (int x = 0; x < 2; ++x) {
            const int fk = fbh + 4 * x;
            const int wk = fk >> 2, dc = fk & 3;
            const int row = k0 + wk * 32 + q5;
            const int col = dc * 16 + hi * 8;
            kld[x][0] = make_float4(0, 0, 0, 0);
            kld[x][1] = kld[x][0];
            if (row < N_) {
                const float4* p = (const float4*)(K + base + (size_t)row * D_ + col);
                kld[x][0] = p[0];
                kld[x][1] = p[1];
            }
        }
        // ---- V: read row pairs, pack to f16 pairs, transposed LDS store
#pragma unroll
        for (int it = 0; it < 2; ++it) {
            const int idx = it * 256 + tid;   // 0..511
            const int p = idx >> 4;           // k-pair 0..31
            const int c4 = (idx & 15) << 2;   // d column
            const int r0 = k0 + 2 * p;
            float4 a = make_float4(0, 0, 0, 0), b = a;
            if (r0 < N_) a = *(const float4*)(V + base + (size_t)r0 * D_ + c4);
            if (r0 + 1 < N_) b = *(const float4*)(V + base + (size_t)(r0 + 1) * D_ + c4);
            VlsU[(c4 + 0) * 36 + p] = pk2(a.x, b.x);
            VlsU[(c4 + 1) * 36 + p] = pk2(a.y, b.y);
            VlsU[(c4 + 2) * 36 + p] = pk2(a.z, b.z);
            VlsU[(c4 + 3) * 36 + p] = pk2(a.w, b.w);
        }
        __syncthreads();
#pragma unroll
        for (int x = 0; x < 2; ++x) {
            const int f = fbh + 4 * x;
            {   // V fragment fv = f = kc*2+dh: one aligned uint4 from LDS
                const int kc = f >> 1, dh = f & 1;
                uint4 u = *(const uint4*)&VlsU[(dh * 32 + q5) * 36 + kc * 8 + hi * 4];
                *(uint4*)&Vf[tb + f * 512 + lane * 8] = u;
            }
            {   // K fragment fk = f from the early loads
                half8 k8;
                float4 a = kld[x][0], b = kld[x][1];
                k8[0] = (_Float16)a.x; k8[1] = (_Float16)a.y;
                k8[2] = (_Float16)a.z; k8[3] = (_Float16)a.w;
                k8[4] = (_Float16)b.x; k8[5] = (_Float16)b.y;
                k8[6] = (_Float16)b.z; k8[7] = (_Float16)b.w;
                *(half8*)&Kf[tb + f * 512 + lane * 8] = k8;
            }
        }
        if (tid < 64) {
            const int kk = k0 + tid;
            const int h = bh % H_;
            const float sgl = LOG2E / (1.f + __expf(-GAMMA[h]));
            float a = 0.f;
            if (kk >= 1 && kk < N_) a = sgl * MU[((size_t)bh * 2 + 1) * N_ + kk];
            akT[bh * 1088 + kk] = a;
        }
    } else {
        const int i = (bid - NBLK) * 256 + tid;
        if (i < TBL_) {
            const float x0 = rel[2 * i + 0], x1 = rel[2 * i + 1];
            float acc[H_];
#pragma unroll
            for (int h = 0; h < H_; ++h) acc[h] = 0.f;
#pragma unroll
            for (int j = 0; j < HID_; ++j) {
                float t = fmaf(x0, w1[j], fmaf(x1, w1[HID_ + j], b1[j]));
                float gl = 0.5f * t * (1.f + erff(t * 0.7071067811865475f));  // exact gelu
#pragma unroll
                for (int h = 0; h < H_; ++h) acc[h] = fmaf(gl, w2[j * H_ + h], acc[h]);
            }
#pragma unroll
            for (int h = 0; h < H_; ++h) btT[h * TBL_ + i] = acc[h];
        }
    }
}

// ---------------- fused flash attention, 32x32x16 MFMA, k-split waves,
// in-register P via cvt_pk + v_permlane32_swap (zero P LDS traffic).
// Wave (wk,wq): QK C[32k-half][32q] over d=64, PV partial O[32q][64d] over its
// k-half; independent online softmax per wave; epilogue pair-merge via LDS.
__global__ __launch_bounds__(256, 3) void flex_attn(
    const float* __restrict__ Q, const _Float16* __restrict__ Kf,
    const _Float16* __restrict__ Vf, const float* __restrict__ MU,
    const float* __restrict__ GAMMA, const char* __restrict__ btb,  // ws - 2048
    const float* __restrict__ akT, float* __restrict__ OUT) {
    __shared__ __align__(16) _Float16 Ks[2][4096];
    __shared__ __align__(16) _Float16 Vs[2][4096];

    const int bid = blockIdx.x;
    const int swz0 = (bid & 7) * (NBLK / 8) + (bid >> 3);  // bijective XCD swizzle
    const int bh = swz0 / NQT;
    const int qt = swz0 % NQT;
    const int h = bh % H_;
    const int tid = threadIdx.x;
    const int w = tid >> 6;
    const int wk = w & 1;        // k-half owner
    const int wq = w >> 1;       // q-half owner
    const int lane = tid & 63;
    const int q5 = lane & 31;    // q (QK) / d (PV) column
    const int hi = lane >> 5;

    const size_t base = (size_t)bh * (N_ * D_);
    const float sg = LOG2E / (1.f + __expf(-GAMMA[h]));

    const int qrow = qt * 64 + wq * 32 + q5;
    const bool qv = qrow < N_;

    // Q B-frags: qf[dc], lane holds Q[qrow][dc*16 + hi*8 + j] * log2e/8
    half8 qf[4];
    const float qs = 0.125f * LOG2E;
#pragma unroll
    for (int dc = 0; dc < 4; ++dc) {
        float4 t0 = make_float4(0, 0, 0, 0), t1 = t0;
        if (qv) {
            const float4* qp = (const float4*)(Q + base + (size_t)qrow * D_ + dc * 16 + hi * 8);
            t0 = qp[0]; t1 = qp[1];
        }
        half8 q8;
        q8[0] = (_Float16)(t0.x * qs); q8[1] = (_Float16)(t0.y * qs);
        q8[2] = (_Float16)(t0.z * qs); q8[3] = (_Float16)(t0.w * qs);
        q8[4] = (_Float16)(t1.x * qs); q8[5] = (_Float16)(t1.y * qs);
        q8[6] = (_Float16)(t1.z * qs); q8[7] = (_Float16)(t1.w * qs);
        qf[dc] = q8;
    }

    const bool qb = qv && (qrow >= 1);
    const float qbf = qb ? 1.f : 0.f;
    float aq = 0.f;
    int cq = 0;
    if (qb) {
        const int pq = qrow - 1;
        cq = (pq >> 5) * 63 + (pq & 31);
        aq = sg * MU[(size_t)bh * 2 * N_ + qrow];  // sg*log2e*mu_q
    }
    // bias byte offsets vs btb = ws-2048; per-tile recurrence: off -= 504
    // score reg r -> k_local = (r&3) + 8*(r>>2) + 4*hi (+ wk*32 global)
    int boffs[16];
#pragma unroll
    for (int r = 0; r < 16; ++r) {
        const int pk = wk * 32 + (r & 3) + 8 * (r >> 2) + 4 * hi - 1;  // tile 0
        const int ck = (pk >> 5) * 63 + (pk & 31);                     // ck(-1) = -32
        boffs[r] = (h * TBL_ + cq + 1984 - ck) * 4 + 2048;
    }
    const float* akb = akT + bh * 1088;
    const _Float16* kfb = Kf + (size_t)bh * NQT * 4096;
    const _Float16* vfb = Vf + (size_t)bh * NQT * 4096;

    f32x16 oA, oB;  // PV partials: d 0-31 / d 32-63; row q=(r&3)+8*(r>>2)+4*hi
#pragma unroll
    for (int r = 0; r < 16; ++r) { oA[r] = 0.f; oB[r] = 0.f; }
    float m = 0.f, l = 0.f;

    // prologue: stage tile 0 (each wave: 2 K-frag chunks + 2 V-frag chunks)
    stage16(kfb + (2 * w + 0) * 512 + lane * 8, &Ks[0][(2 * w + 0) * 512]);
    stage16(kfb + (2 * w + 1) * 512 + lane * 8, &Ks[0][(2 * w + 1) * 512]);
    stage16(vfb + (2 * w + 0) * 512 + lane * 8, &Vs[0][(2 * w + 0) * 512]);
    stage16(vfb + (2 * w + 1) * 512 + lane * 8, &Vs[0][(2 * w + 1) * 512]);
    __syncthreads();

#pragma unroll 1
    for (int t = 0; t < NQT; ++t) {
        const int buf = t & 1;
        const int kt0 = t * 64;

        // ---- bias gathers (L1-resident) + gate k-terms
        float bt16[16];
#pragma unroll
        for (int r = 0; r < 16; ++r) {
            int off = boffs[r];
            off = off < 2048 ? 2048 : off;
            bt16[r] = *(const float*)(btb + (uint32_t)off);
            boffs[r] -= 504;
        }
        f32x4 akq[4];
#pragma unroll
        for (int mi = 0; mi < 4; ++mi)
            akq[mi] = *(const f32x4*)(akb + kt0 + wk * 32 + 8 * mi + 4 * hi);

        // ---- stage next tile
        if (t + 1 < NQT) {
            const _Float16* kn = kfb + (size_t)(t + 1) * 4096;
            const _Float16* vn = vfb + (size_t)(t + 1) * 4096;
            stage16(kn + (2 * w + 0) * 512 + lane * 8, &Ks[buf ^ 1][(2 * w + 0) * 512]);
            stage16(kn + (2 * w + 1) * 512 + lane * 8, &Ks[buf ^ 1][(2 * w + 1) * 512]);
            stage16(vn + (2 * w + 0) * 512 + lane * 8, &Vs[buf ^ 1][(2 * w + 0) * 512]);
            stage16(vn + (2 * w + 1) * 512 + lane * 8, &Vs[buf ^ 1][(2 * w + 1) * 512]);
        }

        // ---- QK^T: C[k-half 32][q 32], reduce d=64 (4 MFMA)
        const _Float16* ksl = &Ks[buf][wk * 2048 + lane * 8];
        f32x16 sa;
#pragma unroll
        for (int r = 0; r < 16; ++r) sa[r] = 0.f;
#pragma unroll
        for (int dc = 0; dc < 4; ++dc) {
            half8 a = *(const half8*)(ksl + dc * 512);
            sa = __builtin_amdgcn_mfma_f32_32x32x16_f16(a, qf[dc], sa, 0, 0, 0);
        }

        // ---- scores (log2 domain)
        if (t == 0 && wk == 0) bt16[0] = hi ? bt16[0] : 0.f;  // k=0: no bias
        float s[16];
#pragma unroll
        for (int r = 0; r < 16; ++r)
            s[r] = fmaf(fmaf(qbf, akq[r >> 2][r & 3], aq), bt16[r], sa[r]);
        if (t == NQT - 1) {  // mask k >= N (only k=1024: wk0,r0,hi0 survives)
#pragma unroll
            for (int r = 0; r < 16; ++r) {
                const bool keep = (wk == 0) && (r == 0) && (hi == 0);
                s[r] = keep ? s[r] : -1e30f;
            }
        }

        // ---- defer-max online softmax (all 16 scores are lane's own q-row)
        float mt = s[0];
#pragma unroll
        for (int r = 1; r < 16; ++r) mt = fmaxf(mt, s[r]);
        if (t == 0) {
            m = fmaxf(mt, __shfl_xor(mt, 32));
        } else if (!__all(mt <= m + THR_)) {
            const float mp = fmaxf(mt, __shfl_xor(mt, 32));
            const float mnew = fmaxf(m, mp);
            const float cc = EX2(m - mnew);
            m = mnew;
            l *= cc;
#pragma unroll
            for (int r = 0; r < 16; ++r) {
                const int qr = (r & 3) + 8 * (r >> 2) + 4 * hi;
                const float ccr = __shfl(cc, qr);
                oA[r] *= ccr;
                oB[r] *= ccr;
            }
        }
        float pv16[16];
        float ls0 = 0.f, ls1 = 0.f;
#pragma unroll
        for (int r = 0; r < 16; r += 2) {
            pv16[r] = EX2(s[r] - m);
            pv16[r + 1] = EX2(s[r + 1] - m);
            ls0 += pv16[r];
            ls1 += pv16[r + 1];
        }
        l += ls0 + ls1;

        // ---- P -> f16 in-register + permlane32_swap into PV A-fragments
        // pk[c=2m+n] packs kk {8m+2n+4hi, +1}; swap(a,b): a'={lo:a_own,hi:b_ptn},
        // b'={lo:a_ptn,hi:b_own} -> (pk0,pk2)->(W0,W2), (pk1,pk3)->(W1,W3), ...
        uint32_t pk[8];
#pragma unroll
        for (int c = 0; c < 8; ++c) {
            const int mi = c >> 1, n = c & 1;
            pk[c] = pk2(pv16[4 * mi + 2 * n], pv16[4 * mi + 2 * n + 1]);
        }
        asm volatile("v_permlane32_swap_b32 %0, %1" : "+v"(pk[0]), "+v"(pk[2]));
        asm volatile("v_permlane32_swap_b32 %0, %1" : "+v"(pk[1]), "+v"(pk[3]));
        asm volatile("v_permlane32_swap_b32 %0, %1" : "+v"(pk[4]), "+v"(pk[6]));
        asm volatile("v_permlane32_swap_b32 %0, %1" : "+v"(pk[5]), "+v"(pk[7]));
        const half8 pa0 = __builtin_bit_cast(half8, make_uint4(pk[0], pk[1], pk[2], pk[3]));
        const half8 pa1 = __builtin_bit_cast(half8, make_uint4(pk[4], pk[5], pk[6], pk[7]));

        // ---- PV: O[q][d] += P[q][k-half] V[k][d]  (4 MFMA, 4 V-frag reads)
        const _Float16* vsl = &Vs[buf][wk * 2048 + lane * 8];
        {
            half8 v0 = *(const half8*)(vsl + 0 * 512);  // kc=2wk+0, d 0-31
            half8 v1 = *(const half8*)(vsl + 1 * 512);  // kc=2wk+0, d 32-63
            half8 v2 = *(const half8*)(vsl + 2 * 512);  // kc=2wk+1, d 0-31
            half8 v3 = *(const half8*)(vsl + 3 * 512);  // kc=2wk+1, d 32-63
            oA = __builtin_amdgcn_mfma_f32_32x32x16_f16(pa0, v0, oA, 0, 0, 0);
            oB = __builtin_amdgcn_mfma_f32_32x32x16_f16(pa0, v1, oB, 0, 0, 0);
            oA = __builtin_amdgcn_mfma_f32_32x32x16_f16(pa1, v2, oA, 0, 0, 0);
            oB = __builtin_amdgcn_mfma_f32_32x32x16_f16(pa1, v3, oB, 0, 0, 0);
        }
        __syncthreads();
    }

    // ---- epilogue: merge wk pairs (independent k-half softmax states)
    const float lq_ = l + __shfl_xor(l, 32);  // full l(q) for this wave's k-half
    float* oxch = (float*)&Ks[0][0];  // [wq][32q][64d] f32 = 2 x 8KB
    float* mlx = (float*)&Vs[0][0];   // [wq][{m,l} x 32]
    if (wk == 1) {
        float* ox = oxch + wq * 2048;
#pragma unroll
        for (int r = 0; r < 16; ++r) {
            const int qr = (r & 3) + 8 * (r >> 2) + 4 * hi;
            ox[qr * 64 + q5] = oA[r];
            ox[qr * 64 + 32 + q5] = oB[r];
        }
        if (hi == 0) {
            mlx[wq * 64 + q5] = m;
            mlx[wq * 64 + 32 + q5] = lq_;
        }
    }
    __syncthreads();
    if (wk == 0) {
        const float m1 = mlx[wq * 64 + q5];
        const float l1 = mlx[wq * 64 + 32 + q5];
        const float ms = fmaxf(m, m1);
        const float c0 = EX2(m - ms), c1 = EX2(m1 - ms);
        const float inv = 1.f / fmaf(lq_, c0, l1 * c1);
        const float f0 = c0 * inv, f1 = c1 * inv;
        const float* ox = oxch + wq * 2048;
#pragma unroll
        for (int r = 0; r < 16; ++r) {
            const int qr = (r & 3) + 8 * (r >> 2) + 4 * hi;
            const float f0r = __shfl(f0, qr);
            const float f1r = __shfl(f1, qr);
            const int qq = qt * 64 + wq * 32 + qr;
            if (qq < N_) {
                float* op = OUT + base + (size_t)qq * D_;
                op[q5] = fmaf(f0r, oA[r], f1r * ox[qr * 64 + q5]);
                op[32 + q5] = fmaf(f0r, oB[r], f1r * ox[qr * 64 + 32 + q5]);
            }
        }
    }
}

extern "C" void kernel_launch(void* const* d_in, const int* in_sizes, int n_in,
                              void* d_out, int out_size, void* d_ws, size_t ws_size,
                              hipStream_t stream) {
    const float* q = (const float*)d_in[0];
    const float* k = (const float*)d_in[1];
    const float* v = (const float*)d_in[2];
    const float* mu = (const float*)d_in[3];
    const float* w1 = (const float*)d_in[4];
    const float* b1 = (const float*)d_in[5];
    const float* w2 = (const float*)d_in[6];
    const float* gamma = (const float*)d_in[7];
    const float* rel = (const float*)d_in[8];
    // d_in[9] = idx_table: reconstructed analytically, never read.

    char* ws = (char*)d_ws;
    float* btT = (float*)(ws + BTT_OFF);
    float* akT = (float*)(ws + AKT_OFF);
    _Float16* Kf = (_Float16*)(ws + KF_OFF);
    _Float16* Vf = (_Float16*)(ws + VF_OFF);

    prep<<<NBLK + (TBL_ + 255) / 256, 256, 0, stream>>>(k, v, mu, gamma, rel, w1, b1, w2,
                                                        Kf, Vf, akT, btT);
    flex_attn<<<NBLK, 256, 0, stream>>>(q, Kf, Vf, mu, gamma, ws - 2048, akT, (float*)d_out);
}

// Round 10
// 75.288 us; speedup vs baseline: 1.0229x; 1.0229x over previous
//
#include <hip/hip_runtime.h>
#include <math.h>

#define B_ 4
#define H_ 12
#define N_ 1025
#define D_ 64
#define HID_ 32
#define TBL_ 3969            // (2*32-1)^2
#define NQT 17               // 64-row tiles in both q and k
#define NBLK (B_ * H_ * NQT) // 816, divisible by 8
#define LOG2E 1.44269504f
#define THR_ 12.0f           // defer-max threshold (log2 domain); p <= 2^12 fits f16

typedef _Float16 half8 __attribute__((ext_vector_type(8)));
typedef __fp16 fp16x2 __attribute__((ext_vector_type(2)));
typedef float f32x4 __attribute__((ext_vector_type(4)));

#if defined(__has_builtin)
#if __has_builtin(__builtin_amdgcn_exp2f)
#define EX2 __builtin_amdgcn_exp2f
#else
#define EX2 exp2f
#endif
#else
#define EX2 exp2f
#endif

// ws layout (bytes):
//   btT @ 0        : 12*3969*4 = 190512
//   akT @ 190512   : 48*1088*4 = 208896   (also the finite overrun pad for btT)
//   Kf  @ 399408   : 48*17*4096*2 = 6684672
//   Vf  @ 7084080  : 6684672              (end 13768752)
#define BTT_OFF 0
#define AKT_OFF 190512
#define KF_OFF 399408
#define VF_OFF 7084080

__device__ __forceinline__ void stage16(const _Float16* gsrc, _Float16* ldst) {
    __builtin_amdgcn_global_load_lds(
        (const __attribute__((address_space(1))) void*)gsrc,
        (__attribute__((address_space(3))) void*)ldst, 16, 0, 0);
}

// ---------------- prep: K/V -> f16 fragment-order tiles (V via LDS transpose),
// akT = sigmoid(gamma)*log2e*mu_k, btT = MLP bias table (per-head transposed)
__global__ __launch_bounds__(256) void prep(
    const float* __restrict__ K, const float* __restrict__ V,
    const float* __restrict__ MU, const float* __restrict__ GAMMA,
    const float* __restrict__ rel, const float* __restrict__ w1,
    const float* __restrict__ b1, const float* __restrict__ w2,
    _Float16* __restrict__ Kf, _Float16* __restrict__ Vf,
    float* __restrict__ akT, float* __restrict__ btT) {
    const int bid = blockIdx.x;
    const int tid = threadIdx.x;
    if (bid < NBLK) {
        __shared__ float Vls[64 * 65];  // [d][k], pad 65 (2-way banks max)
        const int bh = bid / NQT, kt = bid % NQT;
        const size_t base = (size_t)bh * (N_ * D_);
        const int k0 = kt * 64;
        // V rows: coalesced global read -> transposed LDS scatter
#pragma unroll
        for (int it = 0; it < 4; ++it) {
            const int idx = it * 256 + tid;
            const int kr = idx >> 4, c4 = (idx & 15) << 2;
            const int kg = k0 + kr;
            float4 v4 = make_float4(0, 0, 0, 0);
            if (kg < N_) v4 = *(const float4*)(V + base + (size_t)kg * D_ + c4);
            Vls[(c4 + 0) * 65 + kr] = v4.x;
            Vls[(c4 + 1) * 65 + kr] = v4.y;
            Vls[(c4 + 2) * 65 + kr] = v4.z;
            Vls[(c4 + 3) * 65 + kr] = v4.w;
        }
        __syncthreads();
        const int lane = tid & 63, lq = lane & 15, g = lane >> 4;
        const int fbh = tid >> 6;
        const size_t tb = (size_t)(bh * NQT + kt) * 4096;
#pragma unroll
        for (int x = 0; x < 2; ++x) {
            const int fb = fbh + x * 4;
            {   // V fragment fb = kh*4+dg from LDS
                const int kh = fb >> 2, dg = fb & 3;
                const float* vp = &Vls[(dg * 16 + lq) * 65 + kh * 32 + g * 8];
                half8 v8;
#pragma unroll
                for (int j = 0; j < 8; ++j) v8[j] = (_Float16)vp[j];
                *(half8*)&Vf[tb + fb * 512 + lane * 8] = v8;
            }
            {   // K fragment fb = kg2*2+dh, direct
                const int row = k0 + (fb >> 1) * 16 + lq;
                const int col = (fb & 1) * 32 + g * 8;
                half8 k8;
                if (row < N_) {
                    const float4* p = (const float4*)(K + base + (size_t)row * D_ + col);
                    float4 a = p[0], b = p[1];
                    k8[0] = (_Float16)a.x; k8[1] = (_Float16)a.y;
                    k8[2] = (_Float16)a.z; k8[3] = (_Float16)a.w;
                    k8[4] = (_Float16)b.x; k8[5] = (_Float16)b.y;
                    k8[6] = (_Float16)b.z; k8[7] = (_Float16)b.w;
                } else {
#pragma unroll
                    for (int j = 0; j < 8; ++j) k8[j] = (_Float16)0.f;
                }
                *(half8*)&Kf[tb + fb * 512 + lane * 8] = k8;
            }
        }
        if (tid < 64) {
            const int kk = k0 + tid;
            const int h = bh % H_;
            const float sgl = LOG2E / (1.f + __expf(-GAMMA[h]));
            float a = 0.f;
            if (kk >= 1 && kk < N_) a = sgl * MU[((size_t)bh * 2 + 1) * N_ + kk];
            akT[bh * 1088 + kk] = a;
        }
    } else {
        const int i = (bid - NBLK) * 256 + tid;
        if (i < TBL_) {
            const float x0 = rel[2 * i + 0], x1 = rel[2 * i + 1];
            float acc[H_];
#pragma unroll
            for (int h = 0; h < H_; ++h) acc[h] = 0.f;
#pragma unroll
            for (int j = 0; j < HID_; ++j) {
                float t = fmaf(x0, w1[j], fmaf(x1, w1[HID_ + j], b1[j]));
                float gl = 0.5f * t * (1.f + erff(t * 0.7071067811865475f));  // exact gelu
#pragma unroll
                for (int h = 0; h < H_; ++h) acc[h] = fmaf(gl, w2[j * H_ + h], acc[h]);
            }
#pragma unroll
            for (int h = 0; h < H_; ++h) btT[h * TBL_ + i] = acc[h];
        }
    }
}

// ---------------- fused flash attention, f16 MFMA, DMA-staged fragment tiles
// (round-5 structure) + s_setprio around MFMA clusters + balanced max tree
__global__ __launch_bounds__(256, 4) void flex_attn(
    const float* __restrict__ Q, const _Float16* __restrict__ Kf,
    const _Float16* __restrict__ Vf, const float* __restrict__ MU,
    const float* __restrict__ GAMMA, const char* __restrict__ btb,  // ws - 2048
    const float* __restrict__ akT, float* __restrict__ OUT) {
    __shared__ __align__(16) _Float16 Ks[2][4096];
    __shared__ __align__(16) _Float16 Vs[2][4096];
    __shared__ __align__(16) _Float16 Pl[4][1024];  // [wave][16 q][64 k] XOR-swizzled

    const int bid = blockIdx.x;
    const int swz0 = (bid & 7) * (NBLK / 8) + (bid >> 3);  // bijective XCD swizzle
    const int bh = swz0 / NQT;
    const int qt = swz0 % NQT;
    const int h = bh % H_;
    const int tid = threadIdx.x;
    const int w = tid >> 6;
    const int lane = tid & 63;
    const int lq = lane & 15;
    const int g = lane >> 4;

    const size_t base = (size_t)bh * (N_ * D_);
    const float sg = LOG2E / (1.f + __expf(-GAMMA[h]));

    const int qrow = qt * 64 + w * 16 + lq;
    const bool qv = qrow < N_;

    // Q fragment (B-operand of swapped QK^T), scale = log2e/sqrt(64)
    half8 qf[2];
#pragma unroll
    for (int dh = 0; dh < 2; ++dh) {
        float4 t0 = make_float4(0, 0, 0, 0), t1 = t0;
        if (qv) {
            const float4* qp = (const float4*)(Q + base + (size_t)qrow * D_ + dh * 32 + g * 8);
            t0 = qp[0]; t1 = qp[1];
        }
        const float qs = 0.125f * LOG2E;
        half8 q8;
        q8[0] = (_Float16)(t0.x * qs); q8[1] = (_Float16)(t0.y * qs);
        q8[2] = (_Float16)(t0.z * qs); q8[3] = (_Float16)(t0.w * qs);
        q8[4] = (_Float16)(t1.x * qs); q8[5] = (_Float16)(t1.y * qs);
        q8[6] = (_Float16)(t1.z * qs); q8[7] = (_Float16)(t1.w * qs);
        qf[dh] = q8;
    }

    const bool qb = qv && (qrow >= 1);
    const float qbf = qb ? 1.f : 0.f;
    float aq = 0.f;
    int cq = 0;
    if (qb) {
        const int pq = qrow - 1;
        cq = (pq >> 5) * 63 + (pq & 31);
        aq = sg * MU[(size_t)bh * 2 * N_ + qrow];  // sg*log2e*mu_q
    }
    // bias gather byte offsets vs btb = ws-2048: off = (h*TBL + cq + 1984 - ck)*4 + 2048
    // per-tile recurrence: ck += 126 exactly  =>  off -= 504
    int boffs[16];
#pragma unroll
    for (int kg = 0; kg < 4; ++kg) {
#pragma unroll
        for (int r = 0; r < 4; ++r) {
            const int pk = kg * 16 + g * 4 + r - 1;       // tile 0
            const int ck = (pk >> 5) * 63 + (pk & 31);    // arith shift: ck(-1) = -32
            boffs[kg * 4 + r] = (h * TBL_ + cq + 1984 - ck) * 4 + 2048;
        }
    }
    const float* akb = akT + bh * 1088;
    const _Float16* kfb = Kf + (size_t)bh * NQT * 4096;
    const _Float16* vfb = Vf + (size_t)bh * NQT * 4096;

    f32x4 o[4];
    const f32x4 zz = {0.f, 0.f, 0.f, 0.f};
#pragma unroll
    for (int dg = 0; dg < 4; ++dg) o[dg] = zz;
    float m = 0.f, lsum = 0.f;

    // prologue: stage tile 0 into buf 0
    stage16(kfb + (2 * w + 0) * 512 + lane * 8, &Ks[0][(2 * w + 0) * 512]);
    stage16(kfb + (2 * w + 1) * 512 + lane * 8, &Ks[0][(2 * w + 1) * 512]);
    stage16(vfb + (2 * w + 0) * 512 + lane * 8, &Vs[0][(2 * w + 0) * 512]);
    stage16(vfb + (2 * w + 1) * 512 + lane * 8, &Vs[0][(2 * w + 1) * 512]);
    __syncthreads();

    const int pswz = (lq & 7) << 4;
    char* plw = (char*)&Pl[w][0];

    for (int t = 0; t < NQT; ++t) {
        const int buf = t & 1;
        const int kt0 = t * 64;

        // ---- bias gathers (bare saddr loads; clamp floor is a no-op except masked corner)
        float bt16[16];
#pragma unroll
        for (int i = 0; i < 16; ++i) {
            int off = boffs[i];
            off = off < 2048 ? 2048 : off;
            bt16[i] = *(const float*)(btb + (uint32_t)off);
            boffs[i] -= 504;
        }
        // ---- gate k-terms (vectorized, r-consecutive)
        f32x4 akq[4];
#pragma unroll
        for (int kg = 0; kg < 4; ++kg)
            akq[kg] = *(const f32x4*)(akb + kt0 + kg * 16 + g * 4);

        // ---- stage next tile into the other buffer
        if (t + 1 < NQT) {
            const _Float16* kn = kfb + (size_t)(t + 1) * 4096;
            const _Float16* vn = vfb + (size_t)(t + 1) * 4096;
            stage16(kn + (2 * w + 0) * 512 + lane * 8, &Ks[buf ^ 1][(2 * w + 0) * 512]);
            stage16(kn + (2 * w + 1) * 512 + lane * 8, &Ks[buf ^ 1][(2 * w + 1) * 512]);
            stage16(vn + (2 * w + 0) * 512 + lane * 8, &Vs[buf ^ 1][(2 * w + 0) * 512]);
            stage16(vn + (2 * w + 1) * 512 + lane * 8, &Vs[buf ^ 1][(2 * w + 1) * 512]);
        }

        // ---- QK^T (swapped): C[k][q]; A-frags contiguous-by-lane (conflict-free)
        const _Float16* ksl = &Ks[buf][lane * 8];
        f32x4 sa[4];
        __builtin_amdgcn_s_setprio(1);
#pragma unroll
        for (int kg = 0; kg < 4; ++kg) {
            half8 a0 = *(const half8*)(ksl + (2 * kg + 0) * 512);
            half8 a1 = *(const half8*)(ksl + (2 * kg + 1) * 512);
            f32x4 z = zz;
            z = __builtin_amdgcn_mfma_f32_16x16x32_f16(a0, qf[0], z, 0, 0, 0);
            z = __builtin_amdgcn_mfma_f32_16x16x32_f16(a1, qf[1], z, 0, 0, 0);
            sa[kg] = z;
        }
        __builtin_amdgcn_s_setprio(0);

        // ---- scores (log2 domain): s = sa + (qbf*ak + aq)*bt
        if (t == 0 && g == 0) bt16[0] = 0.f;  // k=0 column has no bias
        float s[16];
#pragma unroll
        for (int kg = 0; kg < 4; ++kg) {
#pragma unroll
            for (int r = 0; r < 4; ++r) {
                const int i = kg * 4 + r;
                s[i] = fmaf(fmaf(qbf, akq[kg][r], aq), bt16[i], sa[kg][r]);
            }
        }
        if (t == NQT - 1) {  // mask k >= N (only k=1024 = i0,g0 survives)
#pragma unroll
            for (int kg = 0; kg < 4; ++kg)
#pragma unroll
                for (int r = 0; r < 4; ++r) {
                    const int i = kg * 4 + r;
                    if (1024 + kg * 16 + g * 4 + r >= N_) s[i] = -1e30f;
                }
        }

        // ---- defer-max online softmax; balanced max tree (depth 4, v_max3-friendly)
        float a0_ = fmaxf(s[0], s[1]),   a1_ = fmaxf(s[2], s[3]);
        float a2_ = fmaxf(s[4], s[5]),   a3_ = fmaxf(s[6], s[7]);
        float a4_ = fmaxf(s[8], s[9]),   a5_ = fmaxf(s[10], s[11]);
        float a6_ = fmaxf(s[12], s[13]), a7_ = fmaxf(s[14], s[15]);
        float b0_ = fmaxf(a0_, a1_), b1_ = fmaxf(a2_, a3_);
        float b2_ = fmaxf(a4_, a5_), b3_ = fmaxf(a6_, a7_);
        const float lmax = fmaxf(fmaxf(b0_, b1_), fmaxf(b2_, b3_));
        if (t == 0) {
            float mt = fmaxf(lmax, __shfl_xor(lmax, 16));
            m = fmaxf(mt, __shfl_xor(mt, 32));
        } else if (!__all(lmax <= m + THR_)) {
            float mt = fmaxf(lmax, __shfl_xor(lmax, 16));
            mt = fmaxf(mt, __shfl_xor(mt, 32));
            const float mnew = fmaxf(m, mt);
            const float cc = EX2(m - mnew);
            m = mnew;
            lsum *= cc;
            float cc4[4];
#pragma unroll
            for (int r = 0; r < 4; ++r) cc4[r] = __shfl(cc, g * 4 + r);
#pragma unroll
            for (int dg = 0; dg < 4; ++dg)
#pragma unroll
                for (int r = 0; r < 4; ++r) o[dg][r] *= cc4[r];
        }
        float pv16[16];
        float ls0 = 0.f, ls1 = 0.f, ls2 = 0.f, ls3 = 0.f;
#pragma unroll
        for (int i = 0; i < 16; i += 4) {
            pv16[i] = EX2(s[i] - m);
            pv16[i + 1] = EX2(s[i + 1] - m);
            pv16[i + 2] = EX2(s[i + 2] - m);
            pv16[i + 3] = EX2(s[i + 3] - m);
            ls0 += pv16[i];
            ls1 += pv16[i + 1];
            ls2 += pv16[i + 2];
            ls3 += pv16[i + 3];
        }
        lsum += (ls0 + ls1) + (ls2 + ls3);

        // ---- P -> f16, XOR-swizzled per-wave LDS
#pragma unroll
        for (int kg = 0; kg < 4; ++kg) {
            fp16x2 h0 = __builtin_amdgcn_cvt_pkrtz(pv16[kg * 4 + 0], pv16[kg * 4 + 1]);
            fp16x2 h1 = __builtin_amdgcn_cvt_pkrtz(pv16[kg * 4 + 2], pv16[kg * 4 + 3]);
            uint2 u = make_uint2(__builtin_bit_cast(uint32_t, h0),
                                 __builtin_bit_cast(uint32_t, h1));
            *(uint2*)(plw + lq * 128 + ((kg * 32 + g * 8) ^ pswz)) = u;
        }

        // ---- PV: C[q][d] += P[q][k] V[k][d]
        __builtin_amdgcn_s_setprio(1);
#pragma unroll
        for (int kh = 0; kh < 2; ++kh) {
            half8 pa = *(const half8*)(plw + lq * 128 + ((kh * 64 + g * 16) ^ pswz));
#pragma unroll
            for (int dg = 0; dg < 4; ++dg) {
                half8 vb8 = *(const half8*)&Vs[buf][(kh * 4 + dg) * 512 + lane * 8];
                o[dg] = __builtin_amdgcn_mfma_f32_16x16x32_f16(pa, vb8, o[dg], 0, 0, 0);
            }
        }
        __builtin_amdgcn_s_setprio(0);
        __syncthreads();
    }

    lsum += __shfl_xor(lsum, 16);
    lsum += __shfl_xor(lsum, 32);
    const float linv = 1.f / lsum;
    float li4[4];
#pragma unroll
    for (int r = 0; r < 4; ++r) li4[r] = __shfl(linv, g * 4 + r);
#pragma unroll
    for (int dg = 0; dg < 4; ++dg) {
#pragma unroll
        for (int r = 0; r < 4; ++r) {
            const int qq = qt * 64 + w * 16 + g * 4 + r;
            if (qq < N_) OUT[base + (size_t)qq * D_ + dg * 16 + lq] = o[dg][r] * li4[r];
        }
    }
}

extern "C" void kernel_launch(void* const* d_in, const int* in_sizes, int n_in,
                              void* d_out, int out_size, void* d_ws, size_t ws_size,
                              hipStream_t stream) {
    const float* q = (const float*)d_in[0];
    const float* k = (const float*)d_in[1];
    const float* v = (const float*)d_in[2];
    const float* mu = (const float*)d_in[3];
    const float* w1 = (const float*)d_in[4];
    const float* b1 = (const float*)d_in[5];
    const float* w2 = (const float*)d_in[6];
    const float* gamma = (const float*)d_in[7];
    const float* rel = (const float*)d_in[8];
    // d_in[9] = idx_table: reconstructed analytically, never read.

    char* ws = (char*)d_ws;
    float* btT = (float*)(ws + BTT_OFF);
    float* akT = (float*)(ws + AKT_OFF);
    _Float16* Kf = (_Float16*)(ws + KF_OFF);
    _Float16* Vf = (_Float16*)(ws + VF_OFF);

    prep<<<NBLK + (TBL_ + 255) / 256, 256, 0, stream>>>(k, v, mu, gamma, rel, w1, b1, w2,
                                                        Kf, Vf, akT, btT);
    flex_attn<<<NBLK, 256, 0, stream>>>(q, Kf, Vf, mu, gamma, ws - 2048, akT, (float*)d_out);
}

// Round 11
// 66.030 us; speedup vs baseline: 1.1664x; 1.1402x over previous
//
#include <hip/hip_runtime.h>
#include <math.h>

#define B_ 4
#define H_ 12
#define N_ 1025
#define D_ 64
#define HID_ 32
#define TBL_ 3969            // (2*32-1)^2
#define NQT 17               // 64-row tiles in both q and k
#define NBLK (B_ * H_ * NQT) // 816, divisible by 8
#define LOG2E 1.44269504f
#define THR_ 12.0f           // defer-max threshold (log2 domain); p <= 2^12 fits f16

typedef _Float16 half8 __attribute__((ext_vector_type(8)));
typedef __fp16 fp16x2 __attribute__((ext_vector_type(2)));
typedef float f32x4 __attribute__((ext_vector_type(4)));

#if defined(__has_builtin)
#if __has_builtin(__builtin_amdgcn_exp2f)
#define EX2 __builtin_amdgcn_exp2f
#else
#define EX2 exp2f
#endif
#else
#define EX2 exp2f
#endif

// ws layout (bytes):
//   btT @ 0        : 12*3969*4 = 190512
//   akT @ 190512   : 48*1088*4 = 208896   (also the finite overrun pad for btT)
//   Kf  @ 399408   : 48*17*4096*2 = 6684672
//   Vf  @ 7084080  : 6684672              (end 13768752)
#define BTT_OFF 0
#define AKT_OFF 190512
#define KF_OFF 399408
#define VF_OFF 7084080

__device__ __forceinline__ void stage16(const _Float16* gsrc, _Float16* ldst) {
    __builtin_amdgcn_global_load_lds(
        (const __attribute__((address_space(1))) void*)gsrc,
        (__attribute__((address_space(3))) void*)ldst, 16, 0, 0);
}

// ---------------- prep: K/V -> f16 fragment-order tiles (V via LDS transpose),
// akT = sigmoid(gamma)*log2e*mu_k, btT = MLP bias table (per-head transposed)
__global__ __launch_bounds__(256) void prep(
    const float* __restrict__ K, const float* __restrict__ V,
    const float* __restrict__ MU, const float* __restrict__ GAMMA,
    const float* __restrict__ rel, const float* __restrict__ w1,
    const float* __restrict__ b1, const float* __restrict__ w2,
    _Float16* __restrict__ Kf, _Float16* __restrict__ Vf,
    float* __restrict__ akT, float* __restrict__ btT) {
    const int bid = blockIdx.x;
    const int tid = threadIdx.x;
    if (bid < NBLK) {
        __shared__ float Vls[64 * 65];  // [d][k], pad 65 (2-way banks max)
        const int bh = bid / NQT, kt = bid % NQT;
        const size_t base = (size_t)bh * (N_ * D_);
        const int k0 = kt * 64;
        // V rows: coalesced global read -> transposed LDS scatter
#pragma unroll
        for (int it = 0; it < 4; ++it) {
            const int idx = it * 256 + tid;
            const int kr = idx >> 4, c4 = (idx & 15) << 2;
            const int kg = k0 + kr;
            float4 v4 = make_float4(0, 0, 0, 0);
            if (kg < N_) v4 = *(const float4*)(V + base + (size_t)kg * D_ + c4);
            Vls[(c4 + 0) * 65 + kr] = v4.x;
            Vls[(c4 + 1) * 65 + kr] = v4.y;
            Vls[(c4 + 2) * 65 + kr] = v4.z;
            Vls[(c4 + 3) * 65 + kr] = v4.w;
        }
        __syncthreads();
        const int lane = tid & 63, lq = lane & 15, g = lane >> 4;
        const int fbh = tid >> 6;
        const size_t tb = (size_t)(bh * NQT + kt) * 4096;
#pragma unroll
        for (int x = 0; x < 2; ++x) {
            const int fb = fbh + x * 4;
            {   // V fragment fb = kh*4+dg from LDS
                const int kh = fb >> 2, dg = fb & 3;
                const float* vp = &Vls[(dg * 16 + lq) * 65 + kh * 32 + g * 8];
                half8 v8;
#pragma unroll
                for (int j = 0; j < 8; ++j) v8[j] = (_Float16)vp[j];
                *(half8*)&Vf[tb + fb * 512 + lane * 8] = v8;
            }
            {   // K fragment fb = kg2*2+dh, direct
                const int row = k0 + (fb >> 1) * 16 + lq;
                const int col = (fb & 1) * 32 + g * 8;
                half8 k8;
                if (row < N_) {
                    const float4* p = (const float4*)(K + base + (size_t)row * D_ + col);
                    float4 a = p[0], b = p[1];
                    k8[0] = (_Float16)a.x; k8[1] = (_Float16)a.y;
                    k8[2] = (_Float16)a.z; k8[3] = (_Float16)a.w;
                    k8[4] = (_Float16)b.x; k8[5] = (_Float16)b.y;
                    k8[6] = (_Float16)b.z; k8[7] = (_Float16)b.w;
                } else {
#pragma unroll
                    for (int j = 0; j < 8; ++j) k8[j] = (_Float16)0.f;
                }
                *(half8*)&Kf[tb + fb * 512 + lane * 8] = k8;
            }
        }
        if (tid < 64) {
            const int kk = k0 + tid;
            const int h = bh % H_;
            const float sgl = LOG2E / (1.f + __expf(-GAMMA[h]));
            float a = 0.f;
            if (kk >= 1 && kk < N_) a = sgl * MU[((size_t)bh * 2 + 1) * N_ + kk];
            akT[bh * 1088 + kk] = a;
        }
    } else {
        const int i = (bid - NBLK) * 256 + tid;
        if (i < TBL_) {
            const float x0 = rel[2 * i + 0], x1 = rel[2 * i + 1];
            float acc[H_];
#pragma unroll
            for (int h = 0; h < H_; ++h) acc[h] = 0.f;
#pragma unroll
            for (int j = 0; j < HID_; ++j) {
                float t = fmaf(x0, w1[j], fmaf(x1, w1[HID_ + j], b1[j]));
                float gl = 0.5f * t * (1.f + erff(t * 0.7071067811865475f));  // exact gelu
#pragma unroll
                for (int h = 0; h < H_; ++h) acc[h] = fmaf(gl, w2[j * H_ + h], acc[h]);
            }
#pragma unroll
            for (int h = 0; h < H_; ++h) btT[h * TBL_ + i] = acc[h];
        }
    }
}

// ---------------- fused flash attention, f16 MFMA, DMA-staged fragment tiles
__global__ __launch_bounds__(256, 4) void flex_attn(
    const float* __restrict__ Q, const _Float16* __restrict__ Kf,
    const _Float16* __restrict__ Vf, const float* __restrict__ MU,
    const float* __restrict__ GAMMA, const char* __restrict__ btb,  // ws - 2048
    const float* __restrict__ akT, float* __restrict__ OUT) {
    __shared__ __align__(16) _Float16 Ks[2][4096];
    __shared__ __align__(16) _Float16 Vs[2][4096];
    __shared__ __align__(16) _Float16 Pl[4][1024];  // [wave][16 q][64 k] XOR-swizzled

    const int bid = blockIdx.x;
    const int swz0 = (bid & 7) * (NBLK / 8) + (bid >> 3);  // bijective XCD swizzle
    const int bh = swz0 / NQT;
    const int qt = swz0 % NQT;
    const int h = bh % H_;
    const int tid = threadIdx.x;
    const int w = tid >> 6;
    const int lane = tid & 63;
    const int lq = lane & 15;
    const int g = lane >> 4;

    const size_t base = (size_t)bh * (N_ * D_);
    const float sg = LOG2E / (1.f + __expf(-GAMMA[h]));

    const int qrow = qt * 64 + w * 16 + lq;
    const bool qv = qrow < N_;

    // Q fragment (B-operand of swapped QK^T), scale = log2e/sqrt(64)
    half8 qf[2];
#pragma unroll
    for (int dh = 0; dh < 2; ++dh) {
        float4 t0 = make_float4(0, 0, 0, 0), t1 = t0;
        if (qv) {
            const float4* qp = (const float4*)(Q + base + (size_t)qrow * D_ + dh * 32 + g * 8);
            t0 = qp[0]; t1 = qp[1];
        }
        const float qs = 0.125f * LOG2E;
        half8 q8;
        q8[0] = (_Float16)(t0.x * qs); q8[1] = (_Float16)(t0.y * qs);
        q8[2] = (_Float16)(t0.z * qs); q8[3] = (_Float16)(t0.w * qs);
        q8[4] = (_Float16)(t1.x * qs); q8[5] = (_Float16)(t1.y * qs);
        q8[6] = (_Float16)(t1.z * qs); q8[7] = (_Float16)(t1.w * qs);
        qf[dh] = q8;
    }

    const bool qb = qv && (qrow >= 1);
    const float qbf = qb ? 1.f : 0.f;
    float aq = 0.f;
    int cq = 0;
    if (qb) {
        const int pq = qrow - 1;
        cq = (pq >> 5) * 63 + (pq & 31);
        aq = sg * MU[(size_t)bh * 2 * N_ + qrow];  // sg*log2e*mu_q
    }
    // bias gather byte offsets vs btb = ws-2048: off = (h*TBL + cq + 1984 - ck)*4 + 2048
    // per-tile recurrence: ck += 126 exactly  =>  off -= 504
    int boffs[16];
#pragma unroll
    for (int kg = 0; kg < 4; ++kg) {
#pragma unroll
        for (int r = 0; r < 4; ++r) {
            const int pk = kg * 16 + g * 4 + r - 1;       // tile 0
            const int ck = (pk >> 5) * 63 + (pk & 31);    // arith shift: ck(-1) = -32
            boffs[kg * 4 + r] = (h * TBL_ + cq + 1984 - ck) * 4 + 2048;
        }
    }
    const float* akb = akT + bh * 1088;
    const _Float16* kfb = Kf + (size_t)bh * NQT * 4096;
    const _Float16* vfb = Vf + (size_t)bh * NQT * 4096;

    f32x4 o[4];
    const f32x4 zz = {0.f, 0.f, 0.f, 0.f};
#pragma unroll
    for (int dg = 0; dg < 4; ++dg) o[dg] = zz;
    float m = 0.f, lsum = 0.f;

    // prologue: stage tile 0 into buf 0
    stage16(kfb + (2 * w + 0) * 512 + lane * 8, &Ks[0][(2 * w + 0) * 512]);
    stage16(kfb + (2 * w + 1) * 512 + lane * 8, &Ks[0][(2 * w + 1) * 512]);
    stage16(vfb + (2 * w + 0) * 512 + lane * 8, &Vs[0][(2 * w + 0) * 512]);
    stage16(vfb + (2 * w + 1) * 512 + lane * 8, &Vs[0][(2 * w + 1) * 512]);
    __syncthreads();

    const int pswz = (lq & 7) << 4;
    char* plw = (char*)&Pl[w][0];

    for (int t = 0; t < NQT; ++t) {
        const int buf = t & 1;
        const int kt0 = t * 64;

        // ---- bias gathers (bare saddr loads; clamp floor is a no-op except masked corner)
        float bt16[16];
#pragma unroll
        for (int i = 0; i < 16; ++i) {
            int off = boffs[i];
            off = off < 2048 ? 2048 : off;
            bt16[i] = *(const float*)(btb + (uint32_t)off);
            boffs[i] -= 504;
        }
        // ---- gate k-terms (vectorized, r-consecutive)
        f32x4 akq[4];
#pragma unroll
        for (int kg = 0; kg < 4; ++kg)
            akq[kg] = *(const f32x4*)(akb + kt0 + kg * 16 + g * 4);

        // ---- stage next tile into the other buffer
        if (t + 1 < NQT) {
            const _Float16* kn = kfb + (size_t)(t + 1) * 4096;
            const _Float16* vn = vfb + (size_t)(t + 1) * 4096;
            stage16(kn + (2 * w + 0) * 512 + lane * 8, &Ks[buf ^ 1][(2 * w + 0) * 512]);
            stage16(kn + (2 * w + 1) * 512 + lane * 8, &Ks[buf ^ 1][(2 * w + 1) * 512]);
            stage16(vn + (2 * w + 0) * 512 + lane * 8, &Vs[buf ^ 1][(2 * w + 0) * 512]);
            stage16(vn + (2 * w + 1) * 512 + lane * 8, &Vs[buf ^ 1][(2 * w + 1) * 512]);
        }

        // ---- QK^T (swapped): C[k][q]; A-frags contiguous-by-lane (conflict-free)
        const _Float16* ksl = &Ks[buf][lane * 8];
        f32x4 sa[4];
#pragma unroll
        for (int kg = 0; kg < 4; ++kg) {
            half8 a0 = *(const half8*)(ksl + (2 * kg + 0) * 512);
            half8 a1 = *(const half8*)(ksl + (2 * kg + 1) * 512);
            f32x4 z = zz;
            z = __builtin_amdgcn_mfma_f32_16x16x32_f16(a0, qf[0], z, 0, 0, 0);
            z = __builtin_amdgcn_mfma_f32_16x16x32_f16(a1, qf[1], z, 0, 0, 0);
            sa[kg] = z;
        }

        // ---- scores (log2 domain): s = sa + (qbf*ak + aq)*bt
        if (t == 0 && g == 0) bt16[0] = 0.f;  // k=0 column has no bias
        float s[16];
#pragma unroll
        for (int kg = 0; kg < 4; ++kg) {
#pragma unroll
            for (int r = 0; r < 4; ++r) {
                const int i = kg * 4 + r;
                s[i] = fmaf(fmaf(qbf, akq[kg][r], aq), bt16[i], sa[kg][r]);
            }
        }
        if (t == NQT - 1) {  // mask k >= N (only k=1024 = i0,g0 survives)
#pragma unroll
            for (int kg = 0; kg < 4; ++kg)
#pragma unroll
                for (int r = 0; r < 4; ++r) {
                    const int i = kg * 4 + r;
                    if (1024 + kg * 16 + g * 4 + r >= N_) s[i] = -1e30f;
                }
        }

        // ---- defer-max online softmax: no cross-lane work in the common path
        float lmax = s[0];
#pragma unroll
        for (int i = 1; i < 16; ++i) lmax = fmaxf(lmax, s[i]);
        if (t == 0) {
            float mt = fmaxf(lmax, __shfl_xor(lmax, 16));
            m = fmaxf(mt, __shfl_xor(mt, 32));
        } else if (!__all(lmax <= m + THR_)) {
            float mt = fmaxf(lmax, __shfl_xor(lmax, 16));
            mt = fmaxf(mt, __shfl_xor(mt, 32));
            const float mnew = fmaxf(m, mt);
            const float cc = EX2(m - mnew);
            m = mnew;
            lsum *= cc;
            float cc4[4];
#pragma unroll
            for (int r = 0; r < 4; ++r) cc4[r] = __shfl(cc, g * 4 + r);
#pragma unroll
            for (int dg = 0; dg < 4; ++dg)
#pragma unroll
                for (int r = 0; r < 4; ++r) o[dg][r] *= cc4[r];
        }
        float pv16[16];
        float ls0 = 0.f, ls1 = 0.f;
#pragma unroll
        for (int i = 0; i < 16; i += 2) {
            pv16[i] = EX2(s[i] - m);
            pv16[i + 1] = EX2(s[i + 1] - m);
            ls0 += pv16[i];
            ls1 += pv16[i + 1];
        }
        lsum += ls0 + ls1;

        // ---- P -> f16, XOR-swizzled per-wave LDS
#pragma unroll
        for (int kg = 0; kg < 4; ++kg) {
            fp16x2 h0 = __builtin_amdgcn_cvt_pkrtz(pv16[kg * 4 + 0], pv16[kg * 4 + 1]);
            fp16x2 h1 = __builtin_amdgcn_cvt_pkrtz(pv16[kg * 4 + 2], pv16[kg * 4 + 3]);
            uint2 u = make_uint2(__builtin_bit_cast(uint32_t, h0),
                                 __builtin_bit_cast(uint32_t, h1));
            *(uint2*)(plw + lq * 128 + ((kg * 32 + g * 8) ^ pswz)) = u;
        }

        // ---- PV: C[q][d] += P[q][k] V[k][d]
#pragma unroll
        for (int kh = 0; kh < 2; ++kh) {
            half8 pa = *(const half8*)(plw + lq * 128 + ((kh * 64 + g * 16) ^ pswz));
#pragma unroll
            for (int dg = 0; dg < 4; ++dg) {
                half8 vb8 = *(const half8*)&Vs[buf][(kh * 4 + dg) * 512 + lane * 8];
                o[dg] = __builtin_amdgcn_mfma_f32_16x16x32_f16(pa, vb8, o[dg], 0, 0, 0);
            }
        }
        __syncthreads();
    }

    lsum += __shfl_xor(lsum, 16);
    lsum += __shfl_xor(lsum, 32);
    const float linv = 1.f / lsum;
    float li4[4];
#pragma unroll
    for (int r = 0; r < 4; ++r) li4[r] = __shfl(linv, g * 4 + r);
#pragma unroll
    for (int dg = 0; dg < 4; ++dg) {
#pragma unroll
        for (int r = 0; r < 4; ++r) {
            const int qq = qt * 64 + w * 16 + g * 4 + r;
            if (qq < N_) OUT[base + (size_t)qq * D_ + dg * 16 + lq] = o[dg][r] * li4[r];
        }
    }
}

extern "C" void kernel_launch(void* const* d_in, const int* in_sizes, int n_in,
                              void* d_out, int out_size, void* d_ws, size_t ws_size,
                              hipStream_t stream) {
    const float* q = (const float*)d_in[0];
    const float* k = (const float*)d_in[1];
    const float* v = (const float*)d_in[2];
    const float* mu = (const float*)d_in[3];
    const float* w1 = (const float*)d_in[4];
    const float* b1 = (const float*)d_in[5];
    const float* w2 = (const float*)d_in[6];
    const float* gamma = (const float*)d_in[7];
    const float* rel = (const float*)d_in[8];
    // d_in[9] = idx_table: reconstructed analytically, never read.

    char* ws = (char*)d_ws;
    float* btT = (float*)(ws + BTT_OFF);
    float* akT = (float*)(ws + AKT_OFF);
    _Float16* Kf = (_Float16*)(ws + KF_OFF);
    _Float16* Vf = (_Float16*)(ws + VF_OFF);

    prep<<<NBLK + (TBL_ + 255) / 256, 256, 0, stream>>>(k, v, mu, gamma, rel, w1, b1, w2,
                                                        Kf, Vf, akT, btT);
    flex_attn<<<NBLK, 256, 0, stream>>>(q, Kf, Vf, mu, gamma, ws - 2048, akT, (float*)d_out);
}

// Round 12
// 60.583 us; speedup vs baseline: 1.2712x; 1.0899x over previous
//
#include <hip/hip_runtime.h>
#include <math.h>

#define B_ 4
#define H_ 12
#define N_ 1025
#define D_ 64
#define HID_ 32
#define TBL_ 3969            // (2*32-1)^2
#define NQT 17               // 64-row tiles in both q and k
#define NBLK (B_ * H_ * NQT) // 816, divisible by 8
#define LOG2E 1.44269504f
#define THR_ 12.0f           // defer-max threshold (log2 domain); p <= 2^12 fits f16

typedef _Float16 half8 __attribute__((ext_vector_type(8)));
typedef __fp16 fp16x2 __attribute__((ext_vector_type(2)));
typedef float f32x4 __attribute__((ext_vector_type(4)));
typedef float f32x4u __attribute__((ext_vector_type(4), aligned(4)));  // 4B-aligned float4

#if defined(__has_builtin)
#if __has_builtin(__builtin_amdgcn_exp2f)
#define EX2 __builtin_amdgcn_exp2f
#else
#define EX2 exp2f
#endif
#else
#define EX2 exp2f
#endif

// ws layout (bytes):
//   akT @ 0        : 48*1088*4 = 208896   (also the pad for btR's small underrun)
//   btR @ 208896   : 12*3969*4 = 190512   (REVERSED bias table: btR[h][y]=bt[h][3968-y])
//   Kf  @ 399408   : 48*17*4096*2 = 6684672
//   Vf  @ 7084080  : 6684672              (end 13768752; btR overrun lands in Kf, masked ks only)
#define AKT_OFF 0
#define BTR_OFF 208896
#define KF_OFF 399408
#define VF_OFF 7084080

__device__ __forceinline__ void stage16(const _Float16* gsrc, _Float16* ldst) {
    __builtin_amdgcn_global_load_lds(
        (const __attribute__((address_space(1))) void*)gsrc,
        (__attribute__((address_space(3))) void*)ldst, 16, 0, 0);
}

// ---------------- prep: K/V -> f16 fragment-order tiles (V via LDS transpose),
// akT = sigmoid(gamma)*log2e*mu_k, btR = REVERSED MLP bias table (per-head)
__global__ __launch_bounds__(256) void prep(
    const float* __restrict__ K, const float* __restrict__ V,
    const float* __restrict__ MU, const float* __restrict__ GAMMA,
    const float* __restrict__ rel, const float* __restrict__ w1,
    const float* __restrict__ b1, const float* __restrict__ w2,
    _Float16* __restrict__ Kf, _Float16* __restrict__ Vf,
    float* __restrict__ akT, float* __restrict__ btR) {
    const int bid = blockIdx.x;
    const int tid = threadIdx.x;
    if (bid < NBLK) {
        __shared__ float Vls[64 * 65];  // [d][k], pad 65 (2-way banks max)
        const int bh = bid / NQT, kt = bid % NQT;
        const size_t base = (size_t)bh * (N_ * D_);
        const int k0 = kt * 64;
        // V rows: coalesced global read -> transposed LDS scatter
#pragma unroll
        for (int it = 0; it < 4; ++it) {
            const int idx = it * 256 + tid;
            const int kr = idx >> 4, c4 = (idx & 15) << 2;
            const int kg = k0 + kr;
            float4 v4 = make_float4(0, 0, 0, 0);
            if (kg < N_) v4 = *(const float4*)(V + base + (size_t)kg * D_ + c4);
            Vls[(c4 + 0) * 65 + kr] = v4.x;
            Vls[(c4 + 1) * 65 + kr] = v4.y;
            Vls[(c4 + 2) * 65 + kr] = v4.z;
            Vls[(c4 + 3) * 65 + kr] = v4.w;
        }
        __syncthreads();
        const int lane = tid & 63, lq = lane & 15, g = lane >> 4;
        const int fbh = tid >> 6;
        const size_t tb = (size_t)(bh * NQT + kt) * 4096;
#pragma unroll
        for (int x = 0; x < 2; ++x) {
            const int fb = fbh + x * 4;
            {   // V fragment fb = kh*4+dg from LDS
                const int kh = fb >> 2, dg = fb & 3;
                const float* vp = &Vls[(dg * 16 + lq) * 65 + kh * 32 + g * 8];
                half8 v8;
#pragma unroll
                for (int j = 0; j < 8; ++j) v8[j] = (_Float16)vp[j];
                *(half8*)&Vf[tb + fb * 512 + lane * 8] = v8;
            }
            {   // K fragment fb = kg2*2+dh, direct
                const int row = k0 + (fb >> 1) * 16 + lq;
                const int col = (fb & 1) * 32 + g * 8;
                half8 k8;
                if (row < N_) {
                    const float4* p = (const float4*)(K + base + (size_t)row * D_ + col);
                    float4 a = p[0], b = p[1];
                    k8[0] = (_Float16)a.x; k8[1] = (_Float16)a.y;
                    k8[2] = (_Float16)a.z; k8[3] = (_Float16)a.w;
                    k8[4] = (_Float16)b.x; k8[5] = (_Float16)b.y;
                    k8[6] = (_Float16)b.z; k8[7] = (_Float16)b.w;
                } else {
#pragma unroll
                    for (int j = 0; j < 8; ++j) k8[j] = (_Float16)0.f;
                }
                *(half8*)&Kf[tb + fb * 512 + lane * 8] = k8;
            }
        }
        if (tid < 64) {
            const int kk = k0 + tid;
            const int h = bh % H_;
            const float sgl = LOG2E / (1.f + __expf(-GAMMA[h]));
            float a = 0.f;
            if (kk >= 1 && kk < N_) a = sgl * MU[((size_t)bh * 2 + 1) * N_ + kk];
            akT[bh * 1088 + kk] = a;
        }
    } else {
        const int i = (bid - NBLK) * 256 + tid;
        if (i < TBL_) {
            const float x0 = rel[2 * i + 0], x1 = rel[2 * i + 1];
            float acc[H_];
#pragma unroll
            for (int h = 0; h < H_; ++h) acc[h] = 0.f;
#pragma unroll
            for (int j = 0; j < HID_; ++j) {
                float t = fmaf(x0, w1[j], fmaf(x1, w1[HID_ + j], b1[j]));
                float gl = 0.5f * t * (1.f + erff(t * 0.7071067811865475f));  // exact gelu
#pragma unroll
                for (int h = 0; h < H_; ++h) acc[h] = fmaf(gl, w2[j * H_ + h], acc[h]);
            }
#pragma unroll
            for (int h = 0; h < H_; ++h) btR[h * TBL_ + (TBL_ - 1 - i)] = acc[h];
        }
    }
}

// ---------------- fused flash attention, f16 MFMA, DMA-staged fragment tiles
// (round-5 structure) + quad-vectorized bias gathers via the reversed table
__global__ __launch_bounds__(256, 4) void flex_attn(
    const float* __restrict__ Q, const _Float16* __restrict__ Kf,
    const _Float16* __restrict__ Vf, const float* __restrict__ MU,
    const float* __restrict__ GAMMA, const char* __restrict__ btb,  // = ws + BTR_OFF
    const float* __restrict__ akT, float* __restrict__ OUT) {
    __shared__ __align__(16) _Float16 Ks[2][4096];
    __shared__ __align__(16) _Float16 Vs[2][4096];
    __shared__ __align__(16) _Float16 Pl[4][1024];  // [wave][16 q][64 k] XOR-swizzled

    const int bid = blockIdx.x;
    const int swz0 = (bid & 7) * (NBLK / 8) + (bid >> 3);  // bijective XCD swizzle
    const int bh = swz0 / NQT;
    const int qt = swz0 % NQT;
    const int h = bh % H_;
    const int tid = threadIdx.x;
    const int w = tid >> 6;
    const int lane = tid & 63;
    const int lq = lane & 15;
    const int g = lane >> 4;

    const size_t base = (size_t)bh * (N_ * D_);
    const float sg = LOG2E / (1.f + __expf(-GAMMA[h]));

    const int qrow = qt * 64 + w * 16 + lq;
    const bool qv = qrow < N_;

    // Q fragment (B-operand of swapped QK^T), scale = log2e/sqrt(64)
    half8 qf[2];
#pragma unroll
    for (int dh = 0; dh < 2; ++dh) {
        float4 t0 = make_float4(0, 0, 0, 0), t1 = t0;
        if (qv) {
            const float4* qp = (const float4*)(Q + base + (size_t)qrow * D_ + dh * 32 + g * 8);
            t0 = qp[0]; t1 = qp[1];
        }
        const float qs = 0.125f * LOG2E;
        half8 q8;
        q8[0] = (_Float16)(t0.x * qs); q8[1] = (_Float16)(t0.y * qs);
        q8[2] = (_Float16)(t0.z * qs); q8[3] = (_Float16)(t0.w * qs);
        q8[4] = (_Float16)(t1.x * qs); q8[5] = (_Float16)(t1.y * qs);
        q8[6] = (_Float16)(t1.z * qs); q8[7] = (_Float16)(t1.w * qs);
        qf[dh] = q8;
    }

    const bool qb = qv && (qrow >= 1);
    const float qbf = qb ? 1.f : 0.f;
    float aq = 0.f;
    int cq = 0;
    if (qb) {
        const int pq = qrow - 1;
        cq = (pq >> 5) * 63 + (pq & 31);
        aq = sg * MU[(size_t)bh * 2 * N_ + qrow];  // sg*log2e*mu_q
    }
    // REVERSED table: value(ck) = btR[h*TBL + 1984 - cq + ck] -> forward-consecutive
    // in ck. Per-kg quad r=0..3 has ck consecutive except the quads starting at
    // pk0 % 32 == 31 (exactly g==0 && kg even): there ck(r1) = ck(r0)+32.
    // Per-tile recurrence: ck += 126 -> byte offset += 504.
    int boff4[4];
#pragma unroll
    for (int kg = 0; kg < 4; ++kg) {
        const int pk0 = kg * 16 + g * 4 - 1;              // tile 0
        const int ck0 = (pk0 >> 5) * 63 + (pk0 & 31);     // arith shift: ck0(-1) = -32
        boff4[kg] = (h * TBL_ + 1984 - cq + ck0) * 4;
    }
    const float* akb = akT + bh * 1088;
    const _Float16* kfb = Kf + (size_t)bh * NQT * 4096;
    const _Float16* vfb = Vf + (size_t)bh * NQT * 4096;

    f32x4 o[4];
    const f32x4 zz = {0.f, 0.f, 0.f, 0.f};
#pragma unroll
    for (int dg = 0; dg < 4; ++dg) o[dg] = zz;
    float m = 0.f, lsum = 0.f;

    // prologue: stage tile 0 into buf 0
    stage16(kfb + (2 * w + 0) * 512 + lane * 8, &Ks[0][(2 * w + 0) * 512]);
    stage16(kfb + (2 * w + 1) * 512 + lane * 8, &Ks[0][(2 * w + 1) * 512]);
    stage16(vfb + (2 * w + 0) * 512 + lane * 8, &Vs[0][(2 * w + 0) * 512]);
    stage16(vfb + (2 * w + 1) * 512 + lane * 8, &Vs[0][(2 * w + 1) * 512]);
    __syncthreads();

    const int pswz = (lq & 7) << 4;
    char* plw = (char*)&Pl[w][0];

    for (int t = 0; t < NQT; ++t) {
        const int buf = t & 1;
        const int kt0 = t * 64;

        // ---- bias gathers: 1 float4 (+1 dword for crossing quads) per kg
        float bt16[16];
#pragma unroll
        for (int kg = 0; kg < 4; ++kg) {
            const int off = boff4[kg];
            if (kg & 1) {  // never crosses a 32-row boundary
                f32x4u f4 = *(const f32x4u*)(btb + off);
                bt16[kg * 4 + 0] = f4[0];
                bt16[kg * 4 + 1] = f4[1];
                bt16[kg * 4 + 2] = f4[2];
                bt16[kg * 4 + 3] = f4[3];
            } else {       // g==0 lanes cross: r0 separate, r1..r3 at +32 elements
                const bool cross = (g == 0);
                f32x4u f4 = *(const f32x4u*)(btb + off + (cross ? 128 : 0));
                const float s0v = *(const float*)(btb + off);
                bt16[kg * 4 + 0] = s0v;
                bt16[kg * 4 + 1] = cross ? f4[0] : f4[1];
                bt16[kg * 4 + 2] = cross ? f4[1] : f4[2];
                bt16[kg * 4 + 3] = cross ? f4[2] : f4[3];
            }
            boff4[kg] += 504;
        }
        // ---- gate k-terms (vectorized, r-consecutive)
        f32x4 akq[4];
#pragma unroll
        for (int kg = 0; kg < 4; ++kg)
            akq[kg] = *(const f32x4*)(akb + kt0 + kg * 16 + g * 4);

        // ---- stage next tile into the other buffer
        if (t + 1 < NQT) {
            const _Float16* kn = kfb + (size_t)(t + 1) * 4096;
            const _Float16* vn = vfb + (size_t)(t + 1) * 4096;
            stage16(kn + (2 * w + 0) * 512 + lane * 8, &Ks[buf ^ 1][(2 * w + 0) * 512]);
            stage16(kn + (2 * w + 1) * 512 + lane * 8, &Ks[buf ^ 1][(2 * w + 1) * 512]);
            stage16(vn + (2 * w + 0) * 512 + lane * 8, &Vs[buf ^ 1][(2 * w + 0) * 512]);
            stage16(vn + (2 * w + 1) * 512 + lane * 8, &Vs[buf ^ 1][(2 * w + 1) * 512]);
        }

        // ---- QK^T (swapped): C[k][q]; A-frags contiguous-by-lane (conflict-free)
        const _Float16* ksl = &Ks[buf][lane * 8];
        f32x4 sa[4];
#pragma unroll
        for (int kg = 0; kg < 4; ++kg) {
            half8 a0 = *(const half8*)(ksl + (2 * kg + 0) * 512);
            half8 a1 = *(const half8*)(ksl + (2 * kg + 1) * 512);
            f32x4 z = zz;
            z = __builtin_amdgcn_mfma_f32_16x16x32_f16(a0, qf[0], z, 0, 0, 0);
            z = __builtin_amdgcn_mfma_f32_16x16x32_f16(a1, qf[1], z, 0, 0, 0);
            sa[kg] = z;
        }

        // ---- scores (log2 domain): s = sa + (qbf*ak + aq)*bt
        if (t == 0 && g == 0) bt16[0] = 0.f;  // k=0 column has no bias
        float s[16];
#pragma unroll
        for (int kg = 0; kg < 4; ++kg) {
#pragma unroll
            for (int r = 0; r < 4; ++r) {
                const int i = kg * 4 + r;
                s[i] = fmaf(fmaf(qbf, akq[kg][r], aq), bt16[i], sa[kg][r]);
            }
        }
        if (t == NQT - 1) {  // mask k >= N (only k=1024 = i0,g0 survives)
#pragma unroll
            for (int kg = 0; kg < 4; ++kg)
#pragma unroll
                for (int r = 0; r < 4; ++r) {
                    const int i = kg * 4 + r;
                    if (1024 + kg * 16 + g * 4 + r >= N_) s[i] = -1e30f;
                }
        }

        // ---- defer-max online softmax: no cross-lane work in the common path
        float lmax = s[0];
#pragma unroll
        for (int i = 1; i < 16; ++i) lmax = fmaxf(lmax, s[i]);
        if (t == 0) {
            float mt = fmaxf(lmax, __shfl_xor(lmax, 16));
            m = fmaxf(mt, __shfl_xor(mt, 32));
        } else if (!__all(lmax <= m + THR_)) {
            float mt = fmaxf(lmax, __shfl_xor(lmax, 16));
            mt = fmaxf(mt, __shfl_xor(mt, 32));
            const float mnew = fmaxf(m, mt);
            const float cc = EX2(m - mnew);
            m = mnew;
            lsum *= cc;
            float cc4[4];
#pragma unroll
            for (int r = 0; r < 4; ++r) cc4[r] = __shfl(cc, g * 4 + r);
#pragma unroll
            for (int dg = 0; dg < 4; ++dg)
#pragma unroll
                for (int r = 0; r < 4; ++r) o[dg][r] *= cc4[r];
        }
        float pv16[16];
        float ls0 = 0.f, ls1 = 0.f;
#pragma unroll
        for (int i = 0; i < 16; i += 2) {
            pv16[i] = EX2(s[i] - m);
            pv16[i + 1] = EX2(s[i + 1] - m);
            ls0 += pv16[i];
            ls1 += pv16[i + 1];
        }
        lsum += ls0 + ls1;

        // ---- P -> f16, XOR-swizzled per-wave LDS
#pragma unroll
        for (int kg = 0; kg < 4; ++kg) {
            fp16x2 h0 = __builtin_amdgcn_cvt_pkrtz(pv16[kg * 4 + 0], pv16[kg * 4 + 1]);
            fp16x2 h1 = __builtin_amdgcn_cvt_pkrtz(pv16[kg * 4 + 2], pv16[kg * 4 + 3]);
            uint2 u = make_uint2(__builtin_bit_cast(uint32_t, h0),
                                 __builtin_bit_cast(uint32_t, h1));
            *(uint2*)(plw + lq * 128 + ((kg * 32 + g * 8) ^ pswz)) = u;
        }

        // ---- PV: C[q][d] += P[q][k] V[k][d]
#pragma unroll
        for (int kh = 0; kh < 2; ++kh) {
            half8 pa = *(const half8*)(plw + lq * 128 + ((kh * 64 + g * 16) ^ pswz));
#pragma unroll
            for (int dg = 0; dg < 4; ++dg) {
                half8 vb8 = *(const half8*)&Vs[buf][(kh * 4 + dg) * 512 + lane * 8];
                o[dg] = __builtin_amdgcn_mfma_f32_16x16x32_f16(pa, vb8, o[dg], 0, 0, 0);
            }
        }
        __syncthreads();
    }

    lsum += __shfl_xor(lsum, 16);
    lsum += __shfl_xor(lsum, 32);
    const float linv = 1.f / lsum;
    float li4[4];
#pragma unroll
    for (int r = 0; r < 4; ++r) li4[r] = __shfl(linv, g * 4 + r);
#pragma unroll
    for (int dg = 0; dg < 4; ++dg) {
#pragma unroll
        for (int r = 0; r < 4; ++r) {
            const int qq = qt * 64 + w * 16 + g * 4 + r;
            if (qq < N_) OUT[base + (size_t)qq * D_ + dg * 16 + lq] = o[dg][r] * li4[r];
        }
    }
}

extern "C" void kernel_launch(void* const* d_in, const int* in_sizes, int n_in,
                              void* d_out, int out_size, void* d_ws, size_t ws_size,
                              hipStream_t stream) {
    const float* q = (const float*)d_in[0];
    const float* k = (const float*)d_in[1];
    const float* v = (const float*)d_in[2];
    const float* mu = (const float*)d_in[3];
    const float* w1 = (const float*)d_in[4];
    const float* b1 = (const float*)d_in[5];
    const float* w2 = (const float*)d_in[6];
    const float* gamma = (const float*)d_in[7];
    const float* rel = (const float*)d_in[8];
    // d_in[9] = idx_table: reconstructed analytically, never read.

    char* ws = (char*)d_ws;
    float* akT = (float*)(ws + AKT_OFF);
    float* btR = (float*)(ws + BTR_OFF);
    _Float16* Kf = (_Float16*)(ws + KF_OFF);
    _Float16* Vf = (_Float16*)(ws + VF_OFF);

    prep<<<NBLK + (TBL_ + 255) / 256, 256, 0, stream>>>(k, v, mu, gamma, rel, w1, b1, w2,
                                                        Kf, Vf, akT, btR);
    flex_attn<<<NBLK, 256, 0, stream>>>(q, Kf, Vf, mu, gamma, ws + BTR_OFF, akT,
                                        (float*)d_out);
}